// Round 1
// baseline (549.963 us; speedup 1.0000x reference)
//
#include <hip/hip_runtime.h>
#include <hip/hip_bf16.h>

#define BATCH 4
#define SEQ   2048
#define DM    1024
#define NH    16
#define DK    64
#define BH    (BATCH*NH)   // 64

typedef __attribute__((ext_vector_type(8))) short  bv8;   // 8 bf16 (4 VGPRs) MFMA frag
typedef __attribute__((ext_vector_type(4))) short  sv4;   // 4 bf16 (8B)
typedef __attribute__((ext_vector_type(4))) float  f32x4;

__device__ __forceinline__ short f2b(float f) {
    unsigned u = __builtin_bit_cast(unsigned, f);
    u += 0x7fffu + ((u >> 16) & 1u);          // RNE
    return (short)(u >> 16);
}
__device__ __forceinline__ float b2f(short s) {
    unsigned u = ((unsigned)(unsigned short)s) << 16;
    return __builtin_bit_cast(float, u);
}

// ---------------------------------------------------------------------------
// GEMM (NT): C[m][n] = sum_k A[m][k] * W[n][k].  M=8192, N=1024, K=1024.
// A_BF16: A is bf16 (ctx) else fp32 (x).  FINAL: write fp32 to FO[m*1024+n];
// else blockIdx.z selects (Wq->Oq [BH][S][64]), (Wk->Ok same), (Wv->Ov [BH][64][S] transposed).
// ---------------------------------------------------------------------------
template<bool A_BF16, bool FINAL>
__global__ __launch_bounds__(256) void gemm_nt(
    const float* __restrict__ Af, const short* __restrict__ Abf,
    const float* __restrict__ W0, const float* __restrict__ W1, const float* __restrict__ W2,
    short* __restrict__ Oq, short* __restrict__ Ok, short* __restrict__ Ov,
    float* __restrict__ FO)
{
    constexpr int K = 1024;
    __shared__ __align__(16) short As[128][40];
    __shared__ __align__(16) short Ws[128][40];

    const int bn = blockIdx.x, bm = blockIdx.y, bz = blockIdx.z;
    const float* __restrict__ W = (bz == 0) ? W0 : (bz == 1) ? W1 : W2;
    const int tid = threadIdx.x;
    const int wave = tid >> 6, lane = tid & 63, lm = lane & 15, lq = lane >> 4;
    const int wr = wave >> 1, wc = wave & 1;
    const int row0 = bm * 128, col0 = bn * 128;

    f32x4 acc[4][4];
    for (int i = 0; i < 4; i++)
        for (int j = 0; j < 4; j++)
            acc[i][j] = f32x4{0.f, 0.f, 0.f, 0.f};

    for (int kk = 0; kk < K; kk += 32) {
        // stage A tile (128 x 32) -> bf16 LDS
        if constexpr (A_BF16) {
            for (int p = 0; p < 2; ++p) {
                int lin = p * 2048 + tid * 8;
                int r = lin >> 5, c = lin & 31;
                *(bv8*)&As[r][c] = *(const bv8*)(Abf + (size_t)(row0 + r) * K + kk + c);
            }
        } else {
            for (int p = 0; p < 4; ++p) {
                int lin = p * 1024 + tid * 4;
                int r = lin >> 5, c = lin & 31;
                float4 v = *(const float4*)(Af + (size_t)(row0 + r) * K + kk + c);
                sv4 s; s.x = f2b(v.x); s.y = f2b(v.y); s.z = f2b(v.z); s.w = f2b(v.w);
                *(sv4*)&As[r][c] = s;
            }
        }
        // stage W tile (128 x 32) fp32 -> bf16 LDS
        for (int p = 0; p < 4; ++p) {
            int lin = p * 1024 + tid * 4;
            int r = lin >> 5, c = lin & 31;
            float4 v = *(const float4*)(W + (size_t)(col0 + r) * K + kk + c);
            sv4 s; s.x = f2b(v.x); s.y = f2b(v.y); s.z = f2b(v.z); s.w = f2b(v.w);
            *(sv4*)&Ws[r][c] = s;
        }
        __syncthreads();

        bv8 af[4], bf[4];
        for (int mt = 0; mt < 4; mt++) af[mt] = *(const bv8*)&As[wr * 64 + mt * 16 + lm][lq * 8];
        for (int nt = 0; nt < 4; nt++) bf[nt] = *(const bv8*)&Ws[wc * 64 + nt * 16 + lm][lq * 8];
        for (int mt = 0; mt < 4; mt++)
            for (int nt = 0; nt < 4; nt++)
                acc[mt][nt] = __builtin_amdgcn_mfma_f32_16x16x32_bf16(af[mt], bf[nt], acc[mt][nt], 0, 0, 0);
        __syncthreads();
    }

    // epilogue: D layout col = lane&15, row = (lane>>4)*4 + reg  [m89-verified]
    for (int mt = 0; mt < 4; mt++) {
        int mbase = row0 + wr * 64 + mt * 16 + lq * 4;
        for (int nt = 0; nt < 4; nt++) {
            int n = col0 + wc * 64 + nt * 16 + lm;
            for (int r = 0; r < 4; r++) {
                float v = acc[mt][nt][r];
                int row = mbase + r;
                if constexpr (FINAL) {
                    FO[(size_t)row * 1024 + n] = v;
                } else {
                    int b = row >> 11, s = row & 2047;
                    int h = n >> 6, d = n & 63;
                    if (bz == 2)   // V stored transposed: [BH][64][S]
                        Ov[((size_t)((b * NH + h) * DK + d)) * SEQ + s] = f2b(v);
                    else {
                        short* dst = (bz == 0) ? Oq : Ok;
                        dst[((size_t)((b * NH + h) * SEQ + s)) * DK + d] = f2b(v);
                    }
                }
            }
        }
    }
}

// ---------------------------------------------------------------------------
// RoPE in-place on [BH][S][64] bf16 (Q or K). One thread = 8 elems = 4 pairs.
// out[2i] = t[2i]*cos - t[2i+1]*sin ; out[2i+1] = t[2i]*sin + t[2i+1]*cos
// ---------------------------------------------------------------------------
typedef __attribute__((ext_vector_type(8))) unsigned short usv8;

__global__ __launch_bounds__(256) void rope_kernel(short* __restrict__ T)
{
    int idx = blockIdx.x * 256 + threadIdx.x;     // chunk of 8 elems
    int s  = (idx >> 3) & (SEQ - 1);
    int d0 = (idx & 7) * 8;
    bv8 v = *(const bv8*)(T + (size_t)idx * 8);
    bv8 o;
    for (int j = 0; j < 4; j++) {
        int i = (d0 >> 1) + j;                    // pair index 0..31
        float inv = (float)exp((double)i * -0.28782313662425575); // ln(1e4)/32
        float ang = (float)s * inv;
        float sn, cs;
        sincosf(ang, &sn, &cs);
        float e  = b2f(v[2 * j]);
        float od = b2f(v[2 * j + 1]);
        o[2 * j]     = f2b(e * cs - od * sn);
        o[2 * j + 1] = f2b(e * sn + od * cs);
    }
    *(bv8*)(T + (size_t)idx * 8) = o;
}

// ---------------------------------------------------------------------------
// Flash-style causal attention. grid (S/64, BH), 256 threads = 4 waves.
// Q,K: [BH][S][64] bf16 ; V: [BH][64][S] bf16 (pre-transposed) ; ctx out [B][S][1024] bf16.
// Each wave owns 16 query rows. Online softmax, stats in registers.
// ---------------------------------------------------------------------------
__global__ __launch_bounds__(256) void attn_kernel(
    const short* __restrict__ Qb, const short* __restrict__ Kb,
    const short* __restrict__ Vb, short* __restrict__ Cb)
{
    __shared__ __align__(16) short Qs[64][72];
    __shared__ __align__(16) short Ks[64][72];
    __shared__ __align__(16) short Vts[64][72];   // [d][key]
    __shared__ __align__(16) short Ps[4][16][72]; // per-wave P scratch

    const int qt = blockIdx.x, bh = blockIdx.y;
    const int tid = threadIdx.x, wave = tid >> 6, lane = tid & 63;
    const int lm = lane & 15, lq = lane >> 4;
    const size_t base = (size_t)bh * SEQ * DK;
    const int q0 = qt * 64;

    // stage Q tile
    {
        int r = tid >> 3, c = (tid & 7) * 8;
        for (int p = 0; p < 2; p++) {
            int row = p * 32 + r;
            *(bv8*)&Qs[row][c] = *(const bv8*)(Qb + base + (size_t)(q0 + row) * DK + c);
        }
    }
    __syncthreads();
    bv8 aQ0 = *(const bv8*)&Qs[wave * 16 + lm][lq * 8];
    bv8 aQ1 = *(const bv8*)&Qs[wave * 16 + lm][32 + lq * 8];

    f32x4 oacc[4];
    for (int nt = 0; nt < 4; nt++) oacc[nt] = f32x4{0.f, 0.f, 0.f, 0.f};
    float m_i[4], l_i[4];
    for (int r = 0; r < 4; r++) { m_i[r] = -1e30f; l_i[r] = 0.f; }

    for (int kt = 0; kt <= qt; ++kt) {
        // stage K tile and V^T tile
        {
            int r = tid >> 3, c = (tid & 7) * 8;
            for (int p = 0; p < 2; p++) {
                int row = p * 32 + r;
                *(bv8*)&Ks[row][c]  = *(const bv8*)(Kb + base + (size_t)(kt * 64 + row) * DK + c);
                *(bv8*)&Vts[row][c] = *(const bv8*)(Vb + base + (size_t)row * SEQ + kt * 64 + c);
            }
        }
        __syncthreads();

        // S = Q K^T (16 rows x 64 keys per wave)
        f32x4 sc[4];
        for (int nt = 0; nt < 4; nt++) {
            sc[nt] = f32x4{0.f, 0.f, 0.f, 0.f};
            bv8 b0 = *(const bv8*)&Ks[nt * 16 + lm][lq * 8];
            bv8 b1 = *(const bv8*)&Ks[nt * 16 + lm][32 + lq * 8];
            sc[nt] = __builtin_amdgcn_mfma_f32_16x16x32_bf16(aQ0, b0, sc[nt], 0, 0, 0);
            sc[nt] = __builtin_amdgcn_mfma_f32_16x16x32_bf16(aQ1, b1, sc[nt], 0, 0, 0);
        }
        // scale + causal mask ; row max
        const int qrow = q0 + wave * 16 + lq * 4;
        float rmax[4] = {-1e30f, -1e30f, -1e30f, -1e30f};
        for (int nt = 0; nt < 4; nt++) {
            int key = kt * 64 + nt * 16 + lm;
            for (int r = 0; r < 4; r++) {
                float sv = sc[nt][r] * 0.125f;
                sv = (key <= qrow + r) ? sv : -1e30f;
                sc[nt][r] = sv;
                rmax[r] = fmaxf(rmax[r], sv);
            }
        }
        for (int r = 0; r < 4; r++)
            for (int off = 1; off < 16; off <<= 1)
                rmax[r] = fmaxf(rmax[r], __shfl_xor(rmax[r], off, 64));
        // online softmax update
        float alpha[4], rsum[4];
        for (int r = 0; r < 4; r++) {
            float mn = fmaxf(m_i[r], rmax[r]);
            alpha[r] = __expf(m_i[r] - mn);
            m_i[r] = mn;
            rsum[r] = 0.f;
        }
        for (int nt = 0; nt < 4; nt++)
            for (int r = 0; r < 4; r++) {
                float p = __expf(sc[nt][r] - m_i[r]);
                sc[nt][r] = p;
                rsum[r] += p;
            }
        for (int r = 0; r < 4; r++)
            for (int off = 1; off < 16; off <<= 1)
                rsum[r] += __shfl_xor(rsum[r], off, 64);
        for (int r = 0; r < 4; r++) l_i[r] = l_i[r] * alpha[r] + rsum[r];
        for (int nt = 0; nt < 4; nt++)
            for (int r = 0; r < 4; r++) oacc[nt][r] *= alpha[r];

        // P: C-layout -> LDS -> A-layout (wave-private region)
        for (int nt = 0; nt < 4; nt++)
            for (int r = 0; r < 4; r++)
                Ps[wave][lq * 4 + r][nt * 16 + lm] = f2b(sc[nt][r]);
        asm volatile("s_waitcnt lgkmcnt(0)" ::: "memory");
        bv8 aP0 = *(const bv8*)&Ps[wave][lm][lq * 8];
        bv8 aP1 = *(const bv8*)&Ps[wave][lm][32 + lq * 8];
        for (int nt = 0; nt < 4; nt++) {
            bv8 b0 = *(const bv8*)&Vts[nt * 16 + lm][lq * 8];
            bv8 b1 = *(const bv8*)&Vts[nt * 16 + lm][32 + lq * 8];
            oacc[nt] = __builtin_amdgcn_mfma_f32_16x16x32_bf16(aP0, b0, oacc[nt], 0, 0, 0);
            oacc[nt] = __builtin_amdgcn_mfma_f32_16x16x32_bf16(aP1, b1, oacc[nt], 0, 0, 0);
        }
        __syncthreads();   // all waves done with Ks/Vts before next stage
    }

    // epilogue: ctx[b][s][h*64+d] bf16
    int b = bh >> 4, h = bh & 15;
    for (int r = 0; r < 4; r++) {
        float inv = 1.0f / l_i[r];
        int srow = q0 + wave * 16 + lq * 4 + r;
        size_t rowbase = ((size_t)(b * SEQ + srow)) * DM + h * DK;
        for (int nt = 0; nt < 4; nt++)
            Cb[rowbase + nt * 16 + lm] = f2b(oacc[nt][r] * inv);
    }
}

// ---------------------------------------------------------------------------
extern "C" void kernel_launch(void* const* d_in, const int* in_sizes, int n_in,
                              void* d_out, int out_size, void* d_ws, size_t ws_size,
                              hipStream_t stream)
{
    const float* x  = (const float*)d_in[0];
    const float* Wq = (const float*)d_in[1];
    const float* Wk = (const float*)d_in[2];
    const float* Wv = (const float*)d_in[3];
    const float* Wo = (const float*)d_in[4];
    float* out = (float*)d_out;

    const size_t TSZ = (size_t)BH * SEQ * DK;   // 8,388,608 elems per tensor
    short* Qb = (short*)d_ws;
    short* Kb = Qb + TSZ;
    short* Vb = Kb + TSZ;
    short* Cb = Vb + TSZ;                       // ctx [B][S][1024]

    // QKV projection + V transpose (z: 0=Q,1=K,2=V)
    gemm_nt<false, false><<<dim3(8, 64, 3), 256, 0, stream>>>(
        x, nullptr, Wq, Wk, Wv, Qb, Kb, Vb, nullptr);
    // RoPE on Q and K
    rope_kernel<<<dim3((BH * SEQ * DK / 8) / 256), 256, 0, stream>>>(Qb);
    rope_kernel<<<dim3((BH * SEQ * DK / 8) / 256), 256, 0, stream>>>(Kb);
    // causal flash attention
    attn_kernel<<<dim3(SEQ / 64, BH), 256, 0, stream>>>(Qb, Kb, Vb, Cb);
    // output projection (fp32 out)
    gemm_nt<true, true><<<dim3(8, 64, 1), 256, 0, stream>>>(
        nullptr, Cb, Wo, nullptr, nullptr, nullptr, nullptr, nullptr, out);
}